// Round 3
// baseline (542.260 us; speedup 1.0000x reference)
//
#include <hip/hip_runtime.h>

typedef unsigned short u16;
typedef unsigned int   u32;
typedef __attribute__((ext_vector_type(8))) short s16x8;
typedef __attribute__((ext_vector_type(4))) float f32x4;

#define D_MODEL 1024
#define S_LEN   2048
#define BATCH   4
#define HEADS   16
#define DK      64
#define M_TOTAL (BATCH * S_LEN)   // 8192

// Q scale: 1/sqrt(64) * log2(e)  (scores produced in log2 domain for exp2)
#define QSCALE 0.18033688011112042f
// log2(10000)/32
#define ROPE_L2 0.41524101186092029f

__device__ __forceinline__ u16 f2b(float f) {
  u32 u = __float_as_uint(f);
  u32 r = u + 0x7FFFu + ((u >> 16) & 1u);
  return (u16)(r >> 16);
}
// pack two positive floats to bf16x2 (truncation — P weights only)
__device__ __forceinline__ u32 packtrunc(float f0, float f1) {
  return (__float_as_uint(f0) >> 16) | (__float_as_uint(f1) & 0xFFFF0000u);
}

typedef const __attribute__((address_space(1))) unsigned int* gas_u32p;
typedef __attribute__((address_space(3))) unsigned int* las_u32p;
#define GLL16(gp, lp) __builtin_amdgcn_global_load_lds((gas_u32p)(gp), (las_u32p)(lp), 16, 0, 0)

// ---------------- fp32 -> bf16 convert, 4 elems/thread ----------------
__global__ void k_f2bf(const float* __restrict__ in, u16* __restrict__ out, int n4) {
  int i = blockIdx.x * blockDim.x + threadIdx.x;
  if (i >= n4) return;
  float4 v = ((const float4*)in)[i];
  u32 lo = (u32)f2b(v.x) | ((u32)f2b(v.y) << 16);
  u32 hi = (u32)f2b(v.z) | ((u32)f2b(v.w) << 16);
  ((u32*)out)[2*i]   = lo;
  ((u32*)out)[2*i+1] = hi;
}

// ---------------- GEMM: C[m][n] = sum_k A[m][k] * B[n][k]  (both K-major bf16)
// m97 recipe: 128x128 tile, BK=32, unpadded LDS, global_load_lds width 16.
template<bool BF16OUT, bool ROPE>
__launch_bounds__(256, 4)
__global__ void k_gemm(const u16* __restrict__ A, const u16* __restrict__ B,
                       void* __restrict__ C, int M, int N, int K, float scale) {
  __shared__ u16 Al[128 * 32];
  __shared__ u16 Bl[128 * 32];
  const int tid  = threadIdx.x;
  const int lane = tid & 63;
  const int w    = tid >> 6;
  const int wm   = (w >> 1) * 64, wn = (w & 1) * 64;
  const int bm   = blockIdx.y * 128, bn = blockIdx.x * 128;
  const int row  = lane & 15, q = lane >> 4;

  f32x4 acc[4][4];
#pragma unroll
  for (int i = 0; i < 4; i++)
#pragma unroll
    for (int j = 0; j < 4; j++) acc[i][j] = (f32x4){0.f, 0.f, 0.f, 0.f};

  const int r16 = lane >> 2;
  const int cb  = (lane & 3) * 8;
  const u16* Ag0 = A + (size_t)(bm + w * 32 + r16) * K + cb;
  const u16* Ag1 = Ag0 + (size_t)16 * K;
  const u16* Bg0 = B + (size_t)(bn + w * 32 + r16) * K + cb;
  const u16* Bg1 = Bg0 + (size_t)16 * K;
  u16* Ad0 = Al + (w * 32) * 32;
  u16* Ad1 = Al + (w * 32 + 16) * 32;
  u16* Bd0 = Bl + (w * 32) * 32;
  u16* Bd1 = Bl + (w * 32 + 16) * 32;

  for (int k0 = 0; k0 < K; k0 += 32) {
    __syncthreads();
    GLL16(Ag0 + k0, Ad0);
    GLL16(Ag1 + k0, Ad1);
    GLL16(Bg0 + k0, Bd0);
    GLL16(Bg1 + k0, Bd1);
    __syncthreads();
    s16x8 af[4], bfr[4];
#pragma unroll
    for (int mi = 0; mi < 4; mi++)
      af[mi] = *(const s16x8*)(Al + (wm + mi * 16 + row) * 32 + q * 8);
#pragma unroll
    for (int ni = 0; ni < 4; ni++)
      bfr[ni] = *(const s16x8*)(Bl + (wn + ni * 16 + row) * 32 + q * 8);
#pragma unroll
    for (int mi = 0; mi < 4; mi++)
#pragma unroll
      for (int ni = 0; ni < 4; ni++)
        acc[mi][ni] = __builtin_amdgcn_mfma_f32_16x16x32_bf16(af[mi], bfr[ni], acc[mi][ni], 0, 0, 0);
  }

#pragma unroll
  for (int mi = 0; mi < 4; mi++)
#pragma unroll
    for (int ni = 0; ni < 4; ni++) {
      if (ROPE) {
        const int col = bn + wn + ni * 16 + row;
        const int fi  = (col & 63) >> 1;
        const float inv = exp2f(-(float)fi * ROPE_L2);
        const bool odd = (row & 1);
#pragma unroll
        for (int r = 0; r < 4; r++) {
          int grow = bm + wm + mi * 16 + q * 4 + r;
          float own = acc[mi][ni][r];
          float oth = __shfl_xor(own, 1);
          float ang = (float)(grow & (S_LEN - 1)) * inv;
          float sn, cs;
          __sincosf(ang, &sn, &cs);
          float x1 = odd ? oth : own;
          float x2 = odd ? own : oth;
          float res = odd ? (x1 * sn + x2 * cs) : (x1 * cs - x2 * sn);
          acc[mi][ni][r] = res * scale;
        }
      }
#pragma unroll
      for (int r = 0; r < 4; r++) {
        int grow = bm + wm + mi * 16 + q * 4 + r;
        int gcol = bn + wn + ni * 16 + row;
        float v = acc[mi][ni][r];
        if (BF16OUT) ((u16*)C)[(size_t)grow * N + gcol] = f2b(v);
        else         ((float*)C)[(size_t)grow * N + gcol] = v;
      }
    }
}

// ---------------- flash attention (causal), transposed-S scheme ------------
// S^T = K·Q^T so C-layout lane = q-row, regs = 4 consecutive keys.
// grid: (S/128, HEADS, BATCH), qt reversed; 4 waves; wave w: 32 q-rows (2 mi).
// V pre-transposed: Vtg[h*64+dk][b*2048+s].
__launch_bounds__(256, 3)
__global__ void k_attn(const u16* __restrict__ Qb, const u16* __restrict__ Kb,
                       const u16* __restrict__ Vtg, u16* __restrict__ Mh) {
  __shared__ u16 Kl[128 * 72];       // K-tile [key][dk]
  __shared__ u16 Vt[64 * 136];       // V^T tile [dk][key]
  __shared__ u16 Pl[4 * 16 * 40];    // per-wave P scratch [16 qrow][32 keys+pad]
  const int tid  = threadIdx.x;
  const int lane = tid & 63;
  const int w    = tid >> 6;
  const int row  = lane & 15, q = lane >> 4;
  const int qt = (int)gridDim.x - 1 - (int)blockIdx.x;
  const int h = blockIdx.y, b = blockIdx.z;
  const int q0 = qt * 128;
  const size_t kbase = ((size_t)b * S_LEN) * D_MODEL + (size_t)h * DK;
  const size_t vbase = ((size_t)h * DK) * M_TOTAL + (size_t)b * S_LEN;
  u16* Plw = Pl + w * 16 * 40;

  // Q fragments (B-operand: n = q-row = lane&15, k = dk = q*8+j)
  s16x8 aq[2][2];
#pragma unroll
  for (int mi = 0; mi < 2; mi++) {
    size_t qoff = kbase + (size_t)(q0 + w * 32 + mi * 16 + row) * D_MODEL + q * 8;
    aq[mi][0] = *(const s16x8*)(Qb + qoff);
    aq[mi][1] = *(const s16x8*)(Qb + qoff + 32);
  }

  f32x4 o[2][4];   // O^T accum: col = q-row (lane&15), m = dk (q*4+r | di*16)
#pragma unroll
  for (int mi = 0; mi < 2; mi++)
#pragma unroll
    for (int di = 0; di < 4; di++) o[mi][di] = (f32x4){0.f, 0.f, 0.f, 0.f};
  float lacc[2] = {0.f, 0.f};

  uint4 gk[4], gv[4];
#pragma unroll
  for (int p = 0; p < 4; p++) {
    int idx = p * 256 + tid;
    gk[p] = *(const uint4*)(Kb + kbase + (size_t)(idx >> 3) * D_MODEL + (idx & 7) * 8);
    gv[p] = *(const uint4*)(Vtg + vbase + (size_t)(idx >> 4) * M_TOTAL + (idx & 15) * 8);
  }

  const int ktiles = qt + 1;
  for (int t = 0; t < ktiles; t++) {
    const int k0 = t * 128;
    __syncthreads();
#pragma unroll
    for (int p = 0; p < 4; p++) {
      int idx = p * 256 + tid;
      *(uint4*)(Kl + (idx >> 3) * 72 + (idx & 7) * 8) = gk[p];
      *(uint4*)(Vt + (idx >> 4) * 136 + (idx & 15) * 8) = gv[p];
    }
    __syncthreads();
    if (t + 1 < ktiles) {
      const int kn = k0 + 128;
#pragma unroll
      for (int p = 0; p < 4; p++) {
        int idx = p * 256 + tid;
        gk[p] = *(const uint4*)(Kb + kbase + (size_t)(kn + (idx >> 3)) * D_MODEL + (idx & 7) * 8);
        gv[p] = *(const uint4*)(Vtg + vbase + (size_t)(idx >> 4) * M_TOTAL + kn + (idx & 15) * 8);
      }
    }

#pragma unroll
    for (int ktp = 0; ktp < 4; ktp++) {
      // K A-fragments (shared by both mi) and V^T A-fragments (shared by both mi)
      s16x8 ak[2][2];
#pragma unroll
      for (int kt2 = 0; kt2 < 2; kt2++) {
        const int kt = ktp * 2 + kt2;
        ak[kt2][0] = *(const s16x8*)(Kl + (kt * 16 + row) * 72 + q * 8);
        ak[kt2][1] = *(const s16x8*)(Kl + (kt * 16 + row) * 72 + 32 + q * 8);
      }
      s16x8 vf[4];
#pragma unroll
      for (int di = 0; di < 4; di++)
        vf[di] = *(const s16x8*)(Vt + (di * 16 + row) * 136 + ktp * 32 + q * 8);

#pragma unroll
      for (int mi = 0; mi < 2; mi++) {
        const int rb = q0 + w * 32 + mi * 16;     // wave-uniform q-row base
        f32x4 ss[2];
#pragma unroll
        for (int kt2 = 0; kt2 < 2; kt2++) {
          ss[kt2] = (f32x4){0.f, 0.f, 0.f, 0.f};
          ss[kt2] = __builtin_amdgcn_mfma_f32_16x16x32_bf16(ak[kt2][0], aq[mi][0], ss[kt2], 0, 0, 0);
          ss[kt2] = __builtin_amdgcn_mfma_f32_16x16x32_bf16(ak[kt2][1], aq[mi][1], ss[kt2], 0, 0, 0);
        }
        float psum = 0.f;
#pragma unroll
        for (int kt2 = 0; kt2 < 2; kt2++) {
          const int kb = k0 + (ktp * 2 + kt2) * 16 + q * 4;   // this lane's key base
          const bool needmask = (k0 + (ktp * 2 + kt2) * 16 + 15) > rb;  // wave-uniform
          float p[4];
#pragma unroll
          for (int r = 0; r < 4; r++) {
            float v = ss[kt2][r];
            if (needmask) v = (kb + r <= rb + row) ? v : -1e30f;
            p[r] = exp2f(v);
            psum += p[r];
          }
          u32 lo = packtrunc(p[0], p[1]);
          u32 hi = packtrunc(p[2], p[3]);
          *(uint2*)(Plw + row * 40 + kt2 * 16 + q * 4) = (uint2){lo, hi};
        }
        lacc[mi] += psum;
        // P^T B-fragment read-back: n = q-row(lane&15), k = 8 consecutive keys
        s16x8 pb = *(const s16x8*)(Plw + row * 40 + q * 8);
#pragma unroll
        for (int di = 0; di < 4; di++)
          o[mi][di] = __builtin_amdgcn_mfma_f32_16x16x32_bf16(vf[di], pb, o[mi][di], 0, 0, 0);
      }
    }
  }

  // ---- epilogue: l-reduce across q groups, scale, packed b64 stores ----
#pragma unroll
  for (int mi = 0; mi < 2; mi++) {
    float l = lacc[mi];
    l += __shfl_xor(l, 16);
    l += __shfl_xor(l, 32);
    const float linv = 1.0f / l;
    const int qrow = q0 + w * 32 + mi * 16 + row;
    u16* dst = Mh + ((size_t)b * S_LEN + qrow) * D_MODEL + h * DK + q * 4;
#pragma unroll
    for (int di = 0; di < 4; di++) {
      float v0 = o[mi][di][0] * linv;
      float v1 = o[mi][di][1] * linv;
      float v2 = o[mi][di][2] * linv;
      float v3 = o[mi][di][3] * linv;
      u32 lo = (u32)f2b(v0) | ((u32)f2b(v1) << 16);
      u32 hi = (u32)f2b(v2) | ((u32)f2b(v3) << 16);
      *(uint2*)(dst + di * 16) = (uint2){lo, hi};
    }
  }
}

extern "C" void kernel_launch(void* const* d_in, const int* in_sizes, int n_in,
                              void* d_out, int out_size, void* d_ws, size_t ws_size,
                              hipStream_t stream) {
  const float* x  = (const float*)d_in[0];
  const float* Wq = (const float*)d_in[1];
  const float* Wk = (const float*)d_in[2];
  const float* Wv = (const float*)d_in[3];
  const float* Wo = (const float*)d_in[4];
  float* out = (float*)d_out;

  char* ws = (char*)d_ws;
  const size_t xsz = (size_t)M_TOTAL * D_MODEL * 2;
  const size_t wsz = (size_t)D_MODEL * D_MODEL * 2;
  u16* Xb  = (u16*)ws; ws += xsz;
  u16* Wqb = (u16*)ws; ws += wsz;
  u16* Wkb = (u16*)ws; ws += wsz;
  u16* Wvb = (u16*)ws; ws += wsz;
  u16* Wob = (u16*)ws; ws += wsz;
  u16* Qb  = (u16*)ws; ws += xsz;
  u16* Kb  = (u16*)ws; ws += xsz;
  u16* Vtg = (u16*)ws; ws += xsz;   // V transposed: [1024][8192]
  u16* Mh  = (u16*)ws; ws += xsz;

  {
    int n4 = M_TOTAL * D_MODEL / 4;
    k_f2bf<<<(n4 + 255) / 256, 256, 0, stream>>>(x, Xb, n4);
    n4 = D_MODEL * D_MODEL / 4;
    int blk = (n4 + 255) / 256;
    k_f2bf<<<blk, 256, 0, stream>>>(Wq, Wqb, n4);
    k_f2bf<<<blk, 256, 0, stream>>>(Wk, Wkb, n4);
    k_f2bf<<<blk, 256, 0, stream>>>(Wv, Wvb, n4);
    k_f2bf<<<blk, 256, 0, stream>>>(Wo, Wob, n4);
  }

  dim3 gg(D_MODEL / 128, M_TOTAL / 128);
  k_gemm<true, true><<<gg, 256, 0, stream>>>(Xb, Wqb, Qb, M_TOTAL, D_MODEL, D_MODEL, QSCALE);
  k_gemm<true, true><<<gg, 256, 0, stream>>>(Xb, Wkb, Kb, M_TOTAL, D_MODEL, D_MODEL, 1.0f);
  dim3 gv(M_TOTAL / 128, D_MODEL / 128);
  k_gemm<true, false><<<gv, 256, 0, stream>>>(Wvb, Xb, Vtg, D_MODEL, M_TOTAL, D_MODEL, 1.0f);

  dim3 ga(S_LEN / 128, HEADS, BATCH);
  k_attn<<<ga, 256, 0, stream>>>(Qb, Kb, Vtg, Mh);

  k_gemm<false, false><<<gg, 256, 0, stream>>>(Mh, Wob, out, M_TOTAL, D_MODEL, D_MODEL, 1.0f);
}

// Round 4
// 407.414 us; speedup vs baseline: 1.3310x; 1.3310x over previous
//
#include <hip/hip_runtime.h>

typedef unsigned short u16;
typedef unsigned int   u32;
typedef __attribute__((ext_vector_type(8))) short s16x8;
typedef __attribute__((ext_vector_type(4))) float f32x4;
typedef __attribute__((ext_vector_type(16))) float f32x16;

#define D_MODEL 1024
#define S_LEN   2048
#define BATCH   4
#define HEADS   16
#define DK      64
#define M_TOTAL (BATCH * S_LEN)   // 8192

// Q scale: 1/sqrt(64) * log2(e)  (scores produced in log2 domain for exp2)
#define QSCALE 0.18033688011112042f
// log2(10000)/32
#define ROPE_L2 0.41524101186092029f

__device__ __forceinline__ u16 f2b(float f) {
  u32 u = __float_as_uint(f);
  u32 r = u + 0x7FFFu + ((u >> 16) & 1u);
  return (u16)(r >> 16);
}
// pack two positive floats to bf16x2 (truncation — P weights only)
__device__ __forceinline__ u32 packtrunc(float f0, float f1) {
  return (__float_as_uint(f0) >> 16) | (__float_as_uint(f1) & 0xFFFF0000u);
}

typedef const __attribute__((address_space(1))) unsigned int* gas_u32p;
typedef __attribute__((address_space(3))) unsigned int* las_u32p;
#define GLL16(gp, lp) __builtin_amdgcn_global_load_lds((gas_u32p)(gp), (las_u32p)(lp), 16, 0, 0)

// ---------------- fp32 -> bf16 convert, 4 elems/thread ----------------
__global__ void k_f2bf(const float* __restrict__ in, u16* __restrict__ out, int n4) {
  int i = blockIdx.x * blockDim.x + threadIdx.x;
  if (i >= n4) return;
  float4 v = ((const float4*)in)[i];
  u32 lo = (u32)f2b(v.x) | ((u32)f2b(v.y) << 16);
  u32 hi = (u32)f2b(v.z) | ((u32)f2b(v.w) << 16);
  ((u32*)out)[2*i]   = lo;
  ((u32*)out)[2*i+1] = hi;
}

// ---------------- GEMM: C[m][n] = sum_k A[m][k] * B[n][k]  (both K-major bf16)
// m97 recipe: 128x128 tile, BK=32, unpadded LDS, global_load_lds width 16.
template<bool BF16OUT, bool ROPE>
__launch_bounds__(256, 4)
__global__ void k_gemm(const u16* __restrict__ A, const u16* __restrict__ B,
                       void* __restrict__ C, int M, int N, int K, float scale) {
  __shared__ u16 Al[128 * 32];
  __shared__ u16 Bl[128 * 32];
  const int tid  = threadIdx.x;
  const int lane = tid & 63;
  const int w    = tid >> 6;
  const int wm   = (w >> 1) * 64, wn = (w & 1) * 64;
  const int bm   = blockIdx.y * 128, bn = blockIdx.x * 128;
  const int row  = lane & 15, q = lane >> 4;

  f32x4 acc[4][4];
#pragma unroll
  for (int i = 0; i < 4; i++)
#pragma unroll
    for (int j = 0; j < 4; j++) acc[i][j] = (f32x4){0.f, 0.f, 0.f, 0.f};

  const int r16 = lane >> 2;
  const int cb  = (lane & 3) * 8;
  const u16* Ag0 = A + (size_t)(bm + w * 32 + r16) * K + cb;
  const u16* Ag1 = Ag0 + (size_t)16 * K;
  const u16* Bg0 = B + (size_t)(bn + w * 32 + r16) * K + cb;
  const u16* Bg1 = Bg0 + (size_t)16 * K;
  u16* Ad0 = Al + (w * 32) * 32;
  u16* Ad1 = Al + (w * 32 + 16) * 32;
  u16* Bd0 = Bl + (w * 32) * 32;
  u16* Bd1 = Bl + (w * 32 + 16) * 32;

  for (int k0 = 0; k0 < K; k0 += 32) {
    __syncthreads();
    GLL16(Ag0 + k0, Ad0);
    GLL16(Ag1 + k0, Ad1);
    GLL16(Bg0 + k0, Bd0);
    GLL16(Bg1 + k0, Bd1);
    __syncthreads();
    s16x8 af[4], bfr[4];
#pragma unroll
    for (int mi = 0; mi < 4; mi++)
      af[mi] = *(const s16x8*)(Al + (wm + mi * 16 + row) * 32 + q * 8);
#pragma unroll
    for (int ni = 0; ni < 4; ni++)
      bfr[ni] = *(const s16x8*)(Bl + (wn + ni * 16 + row) * 32 + q * 8);
#pragma unroll
    for (int mi = 0; mi < 4; mi++)
#pragma unroll
      for (int ni = 0; ni < 4; ni++)
        acc[mi][ni] = __builtin_amdgcn_mfma_f32_16x16x32_bf16(af[mi], bfr[ni], acc[mi][ni], 0, 0, 0);
  }

#pragma unroll
  for (int mi = 0; mi < 4; mi++)
#pragma unroll
    for (int ni = 0; ni < 4; ni++) {
      if (ROPE) {
        const int col = bn + wn + ni * 16 + row;
        const int fi  = (col & 63) >> 1;
        const float inv = exp2f(-(float)fi * ROPE_L2);
        const bool odd = (row & 1);
#pragma unroll
        for (int r = 0; r < 4; r++) {
          int grow = bm + wm + mi * 16 + q * 4 + r;
          float own = acc[mi][ni][r];
          float oth = __shfl_xor(own, 1);
          float ang = (float)(grow & (S_LEN - 1)) * inv;
          float sn, cs;
          __sincosf(ang, &sn, &cs);
          float x1 = odd ? oth : own;
          float x2 = odd ? own : oth;
          float res = odd ? (x1 * sn + x2 * cs) : (x1 * cs - x2 * sn);
          acc[mi][ni][r] = res * scale;
        }
      }
#pragma unroll
      for (int r = 0; r < 4; r++) {
        int grow = bm + wm + mi * 16 + q * 4 + r;
        int gcol = bn + wn + ni * 16 + row;
        float v = acc[mi][ni][r];
        if (BF16OUT) ((u16*)C)[(size_t)grow * N + gcol] = f2b(v);
        else         ((float*)C)[(size_t)grow * N + gcol] = v;
      }
    }
}

// ---------------- flash attention (causal), 32x32 MFMA, no P-LDS -----------
// S^T = K·Q^T via 32x32x16: C-layout lane col = q-row, regs = 16 keys.
// P C-frag -> PV B-frag via 2x shfl_xor(32) + cndmask (no LDS round trip).
// grid: (S/128, HEADS, BATCH), qt reversed; 4 waves; wave w: q-rows [qw, qw+32).
// V pre-transposed: Vtg[h*64+dk][b*2048+s].
__launch_bounds__(256, 3)
__global__ void k_attn(const u16* __restrict__ Qb, const u16* __restrict__ Kb,
                       const u16* __restrict__ Vtg, u16* __restrict__ Mh) {
  __shared__ u16 Kl[128 * 72];       // K-tile [key][dk]
  __shared__ u16 Vt[64 * 136];       // V^T tile [dk][key]
  const int tid  = threadIdx.x;
  const int lane = tid & 63;
  const int w    = tid >> 6;
  const int n    = lane & 31;        // q-row (S^T,PV n-dim) / dk (PV m-dim) / key (S^T m-dim)
  const int h    = lane >> 5;        // lane half
  const int qt = (int)gridDim.x - 1 - (int)blockIdx.x;
  const int hd = blockIdx.y, b = blockIdx.z;
  const int q0 = qt * 128;
  const int qw = q0 + w * 32;        // wave's q-row base
  const size_t kbase = ((size_t)b * S_LEN) * D_MODEL + (size_t)hd * DK;
  const size_t vbase = ((size_t)hd * DK) * M_TOTAL + (size_t)b * S_LEN;

  // Q B-frags (n = q-row = lane&31, k = dk = ks*16 + h*8 + j), held in regs
  s16x8 bq[4];
#pragma unroll
  for (int ks = 0; ks < 4; ks++)
    bq[ks] = *(const s16x8*)(Qb + kbase + (size_t)(qw + n) * D_MODEL + ks * 16 + h * 8);

  // O^T accumulators: dt = dk-half (0..1); C-layout col = q-row, rows = dk
  f32x16 o0, o1;
#pragma unroll
  for (int i = 0; i < 16; i++) { o0[i] = 0.f; o1[i] = 0.f; }
  float psum = 0.f;

  uint4 gk[4], gv[4];
#pragma unroll
  for (int p = 0; p < 4; p++) {
    int idx = p * 256 + tid;
    gk[p] = *(const uint4*)(Kb + kbase + (size_t)(idx >> 3) * D_MODEL + (idx & 7) * 8);
    gv[p] = *(const uint4*)(Vtg + vbase + (size_t)(idx >> 4) * M_TOTAL + (idx & 15) * 8);
  }

  const int ktiles = qt + 1;
  for (int t = 0; t < ktiles; t++) {
    const int k0 = t * 128;
    __syncthreads();
#pragma unroll
    for (int p = 0; p < 4; p++) {
      int idx = p * 256 + tid;
      *(uint4*)(Kl + (idx >> 3) * 72 + (idx & 7) * 8) = gk[p];
      *(uint4*)(Vt + (idx >> 4) * 136 + (idx & 15) * 8) = gv[p];
    }
    __syncthreads();
    if (t + 1 < ktiles) {
      const int kn = k0 + 128;
#pragma unroll
      for (int p = 0; p < 4; p++) {
        int idx = p * 256 + tid;
        gk[p] = *(const uint4*)(Kb + kbase + (size_t)(kn + (idx >> 3)) * D_MODEL + (idx & 7) * 8);
        gv[p] = *(const uint4*)(Vtg + vbase + (size_t)(idx >> 4) * M_TOTAL + kn + (idx & 15) * 8);
      }
    }

#pragma unroll
    for (int kt = 0; kt < 4; kt++) {
      const int k0t = k0 + kt * 32;
      if (k0t > qw + 31) continue;          // fully masked 32-key sub-tile (wave-uniform)

      // ---- S^T[32 keys][32 qrows] = K · Q^T over dk=64 (4 k-steps) ----
      f32x16 Sc;
#pragma unroll
      for (int i = 0; i < 16; i++) Sc[i] = 0.f;
#pragma unroll
      for (int ks = 0; ks < 4; ks++) {
        s16x8 ak = *(const s16x8*)(Kl + (kt * 32 + n) * 72 + ks * 16 + h * 8);
        Sc = __builtin_amdgcn_mfma_f32_32x32x16_bf16(ak, bq[ks], Sc, 0, 0, 0);
      }

      // ---- mask + exp2 + pack: lane holds key = k0t + 8g + t2 + 4h, qrow = qw + n
      const bool needmask = (k0t + 31) > qw;
      u32 P0[4], P1[4];
#pragma unroll
      for (int g = 0; g < 4; g++) {
        float p[4];
#pragma unroll
        for (int t2 = 0; t2 < 4; t2++) {
          float v = Sc[4 * g + t2];
          if (needmask) {
            int key = k0t + 8 * g + t2 + 4 * h;
            v = (key <= qw + n) ? v : -1e30f;
          }
          p[t2] = exp2f(v);
          psum += p[t2];
        }
        P0[g] = packtrunc(p[0], p[1]);
        P1[g] = packtrunc(p[2], p[3]);
      }

      // ---- PV: for each 16-key chunk c, build P^T B-frag via half-lane swap
#pragma unroll
      for (int c = 0; c < 2; c++) {
        u32 X0 = h ? P0[2 * c + 1] : P0[2 * c];
        u32 X1 = h ? P1[2 * c + 1] : P1[2 * c];
        u32 Y0 = h ? P0[2 * c]     : P0[2 * c + 1];
        u32 Y1 = h ? P1[2 * c]     : P1[2 * c + 1];
        u32 Z0 = (u32)__shfl_xor((int)Y0, 32);
        u32 Z1 = (u32)__shfl_xor((int)Y1, 32);
        union { u32 u[4]; s16x8 v; } pb;
        pb.u[0] = h ? Z0 : X0;
        pb.u[1] = h ? Z1 : X1;
        pb.u[2] = h ? X0 : Z0;
        pb.u[3] = h ? X1 : Z1;
        {
          s16x8 vf0 = *(const s16x8*)(Vt + (0 * 32 + n) * 136 + kt * 32 + c * 16 + h * 8);
          o0 = __builtin_amdgcn_mfma_f32_32x32x16_bf16(vf0, pb.v, o0, 0, 0, 0);
          s16x8 vf1 = *(const s16x8*)(Vt + (1 * 32 + n) * 136 + kt * 32 + c * 16 + h * 8);
          o1 = __builtin_amdgcn_mfma_f32_32x32x16_bf16(vf1, pb.v, o1, 0, 0, 0);
        }
      }
    }
  }

  // ---- epilogue: l = psum + other half; scale; packed 8B stores ----
  float l = psum + __shfl_xor(psum, 32);
  const float linv = 1.0f / l;
  const int qrow = qw + n;
  u16* dst = Mh + ((size_t)b * S_LEN + qrow) * D_MODEL + hd * DK;
#pragma unroll
  for (int dt = 0; dt < 2; dt++) {
    const f32x16& o = dt ? o1 : o0;
#pragma unroll
    for (int g = 0; g < 4; g++) {
      float v0 = o[4 * g + 0] * linv;
      float v1 = o[4 * g + 1] * linv;
      float v2 = o[4 * g + 2] * linv;
      float v3 = o[4 * g + 3] * linv;
      u32 lo = (u32)f2b(v0) | ((u32)f2b(v1) << 16);
      u32 hi = (u32)f2b(v2) | ((u32)f2b(v3) << 16);
      *(uint2*)(dst + dt * 32 + 8 * g + 4 * h) = (uint2){lo, hi};
    }
  }
}

extern "C" void kernel_launch(void* const* d_in, const int* in_sizes, int n_in,
                              void* d_out, int out_size, void* d_ws, size_t ws_size,
                              hipStream_t stream) {
  const float* x  = (const float*)d_in[0];
  const float* Wq = (const float*)d_in[1];
  const float* Wk = (const float*)d_in[2];
  const float* Wv = (const float*)d_in[3];
  const float* Wo = (const float*)d_in[4];
  float* out = (float*)d_out;

  char* ws = (char*)d_ws;
  const size_t xsz = (size_t)M_TOTAL * D_MODEL * 2;
  const size_t wsz = (size_t)D_MODEL * D_MODEL * 2;
  u16* Xb  = (u16*)ws; ws += xsz;
  u16* Wqb = (u16*)ws; ws += wsz;
  u16* Wkb = (u16*)ws; ws += wsz;
  u16* Wvb = (u16*)ws; ws += wsz;
  u16* Wob = (u16*)ws; ws += wsz;
  u16* Qb  = (u16*)ws; ws += xsz;
  u16* Kb  = (u16*)ws; ws += xsz;
  u16* Vtg = (u16*)ws; ws += xsz;   // V transposed: [1024][8192]
  u16* Mh  = (u16*)ws; ws += xsz;

  {
    int n4 = M_TOTAL * D_MODEL / 4;
    k_f2bf<<<(n4 + 255) / 256, 256, 0, stream>>>(x, Xb, n4);
    n4 = D_MODEL * D_MODEL / 4;
    int blk = (n4 + 255) / 256;
    k_f2bf<<<blk, 256, 0, stream>>>(Wq, Wqb, n4);
    k_f2bf<<<blk, 256, 0, stream>>>(Wk, Wkb, n4);
    k_f2bf<<<blk, 256, 0, stream>>>(Wv, Wvb, n4);
    k_f2bf<<<blk, 256, 0, stream>>>(Wo, Wob, n4);
  }

  dim3 gg(D_MODEL / 128, M_TOTAL / 128);
  k_gemm<true, true><<<gg, 256, 0, stream>>>(Xb, Wqb, Qb, M_TOTAL, D_MODEL, D_MODEL, QSCALE);
  k_gemm<true, true><<<gg, 256, 0, stream>>>(Xb, Wkb, Kb, M_TOTAL, D_MODEL, D_MODEL, 1.0f);
  dim3 gv(M_TOTAL / 128, D_MODEL / 128);
  k_gemm<true, false><<<gv, 256, 0, stream>>>(Wvb, Xb, Vtg, D_MODEL, M_TOTAL, D_MODEL, 1.0f);

  dim3 ga(S_LEN / 128, HEADS, BATCH);
  k_attn<<<ga, 256, 0, stream>>>(Qb, Kb, Vtg, Mh);

  k_gemm<false, false><<<gg, 256, 0, stream>>>(Mh, Wob, out, M_TOTAL, D_MODEL, D_MODEL, 1.0f);
}

// Round 5
// 403.962 us; speedup vs baseline: 1.3424x; 1.0085x over previous
//
#include <hip/hip_runtime.h>

typedef unsigned short u16;
typedef unsigned int   u32;
typedef __attribute__((ext_vector_type(8))) short s16x8;
typedef __attribute__((ext_vector_type(4))) float f32x4;
typedef __attribute__((ext_vector_type(16))) float f32x16;

#define D_MODEL 1024
#define S_LEN   2048
#define BATCH   4
#define HEADS   16
#define DK      64
#define M_TOTAL (BATCH * S_LEN)   // 8192

// Q scale: 1/sqrt(64) * log2(e)  (scores produced in log2 domain for exp2)
#define QSCALE 0.18033688011112042f
// log2(10000)/32
#define ROPE_L2 0.41524101186092029f

__device__ __forceinline__ u16 f2b(float f) {
  u32 u = __float_as_uint(f);
  u32 r = u + 0x7FFFu + ((u >> 16) & 1u);
  return (u16)(r >> 16);
}
// pack two positive floats to bf16x2 (truncation — P weights only)
__device__ __forceinline__ u32 packtrunc(float f0, float f1) {
  return (__float_as_uint(f0) >> 16) | (__float_as_uint(f1) & 0xFFFF0000u);
}
// round-to-nearest pack
__device__ __forceinline__ u32 packrn(float f0, float f1) {
  return (u32)f2b(f0) | ((u32)f2b(f1) << 16);
}

typedef const __attribute__((address_space(1))) unsigned int* gas_u32p;
typedef __attribute__((address_space(3))) unsigned int* las_u32p;
#define GLL16(gp, lp) __builtin_amdgcn_global_load_lds((gas_u32p)(gp), (las_u32p)(lp), 16, 0, 0)

// ---------------- fp32 -> bf16 convert, 4 elems/thread ----------------
__global__ void k_f2bf(const float* __restrict__ in, u16* __restrict__ out, int n4) {
  int i = blockIdx.x * blockDim.x + threadIdx.x;
  if (i >= n4) return;
  float4 v = ((const float4*)in)[i];
  ((u32*)out)[2*i]   = packrn(v.x, v.y);
  ((u32*)out)[2*i+1] = packrn(v.z, v.w);
}

// ---------------- GEMM: C[m][n] = sum_k A[m][k] * B[n][k]  (both K-major bf16)
// m97 recipe: 128x128 tile, BK=32, unpadded LDS, global_load_lds width 16.
template<bool BF16OUT, bool ROPE>
__launch_bounds__(256, 4)
__global__ void k_gemm(const u16* __restrict__ A, const u16* __restrict__ B,
                       void* __restrict__ C, int M, int N, int K, float scale) {
  __shared__ u16 Al[128 * 32];
  __shared__ u16 Bl[128 * 32];
  const int tid  = threadIdx.x;
  const int lane = tid & 63;
  const int w    = tid >> 6;
  const int wm   = (w >> 1) * 64, wn = (w & 1) * 64;
  const int bm   = blockIdx.y * 128, bn = blockIdx.x * 128;
  const int row  = lane & 15, q = lane >> 4;

  f32x4 acc[4][4];
#pragma unroll
  for (int i = 0; i < 4; i++)
#pragma unroll
    for (int j = 0; j < 4; j++) acc[i][j] = (f32x4){0.f, 0.f, 0.f, 0.f};

  const int r16 = lane >> 2;
  const int cb  = (lane & 3) * 8;
  const u16* Ag0 = A + (size_t)(bm + w * 32 + r16) * K + cb;
  const u16* Ag1 = Ag0 + (size_t)16 * K;
  const u16* Bg0 = B + (size_t)(bn + w * 32 + r16) * K + cb;
  const u16* Bg1 = Bg0 + (size_t)16 * K;
  u16* Ad0 = Al + (w * 32) * 32;
  u16* Ad1 = Al + (w * 32 + 16) * 32;
  u16* Bd0 = Bl + (w * 32) * 32;
  u16* Bd1 = Bl + (w * 32 + 16) * 32;

  for (int k0 = 0; k0 < K; k0 += 32) {
    __syncthreads();
    GLL16(Ag0 + k0, Ad0);
    GLL16(Ag1 + k0, Ad1);
    GLL16(Bg0 + k0, Bd0);
    GLL16(Bg1 + k0, Bd1);
    __syncthreads();
    s16x8 af[4], bfr[4];
#pragma unroll
    for (int mi = 0; mi < 4; mi++)
      af[mi] = *(const s16x8*)(Al + (wm + mi * 16 + row) * 32 + q * 8);
#pragma unroll
    for (int ni = 0; ni < 4; ni++)
      bfr[ni] = *(const s16x8*)(Bl + (wn + ni * 16 + row) * 32 + q * 8);
#pragma unroll
    for (int mi = 0; mi < 4; mi++)
#pragma unroll
      for (int ni = 0; ni < 4; ni++)
        acc[mi][ni] = __builtin_amdgcn_mfma_f32_16x16x32_bf16(af[mi], bfr[ni], acc[mi][ni], 0, 0, 0);
  }

#pragma unroll
  for (int mi = 0; mi < 4; mi++)
#pragma unroll
    for (int ni = 0; ni < 4; ni++) {
      if (ROPE) {
        const int col = bn + wn + ni * 16 + row;
        const int fi  = (col & 63) >> 1;
        const float inv = exp2f(-(float)fi * ROPE_L2);
        const bool odd = (row & 1);
#pragma unroll
        for (int r = 0; r < 4; r++) {
          int grow = bm + wm + mi * 16 + q * 4 + r;
          float own = acc[mi][ni][r];
          float oth = __shfl_xor(own, 1);
          float ang = (float)(grow & (S_LEN - 1)) * inv;
          float sn, cs;
          __sincosf(ang, &sn, &cs);
          float x1 = odd ? oth : own;
          float x2 = odd ? own : oth;
          float res = odd ? (x1 * sn + x2 * cs) : (x1 * cs - x2 * sn);
          acc[mi][ni][r] = res * scale;
        }
      }
#pragma unroll
      for (int r = 0; r < 4; r++) {
        int grow = bm + wm + mi * 16 + q * 4 + r;
        int gcol = bn + wn + ni * 16 + row;
        float v = acc[mi][ni][r];
        if (BF16OUT) ((u16*)C)[(size_t)grow * N + gcol] = f2b(v);
        else         ((float*)C)[(size_t)grow * N + gcol] = v;
      }
    }
}

// ---------------- flash attention (causal), 32x32 MFMA, no P-LDS -----------
// S^T = K·Q^T via 32x32x16: C-layout lane col = q-row, regs = 16 keys.
// P C-frag -> PV B-frag via shfl_xor(32) + select (no LDS round trip).
// 1-D grid 1024 blocks, XCD-swizzled: bid&7 pins all 16 q-tiles of one (b,h)
// to one XCD (K/V = 512 KB << 4 MB L2); qt descending within each XCD.
// V pre-transposed: Vtg[h*64+dk][b*2048+s]. Epilogue transposes O through LDS
// so every global store instruction writes full 128B row segments.
__launch_bounds__(256, 4)
__global__ void k_attn(const u16* __restrict__ Qb, const u16* __restrict__ Kb,
                       const u16* __restrict__ Vtg, u16* __restrict__ Mh) {
  __shared__ u16 Kl[128 * 72];       // K-tile [key][dk]; reused as O scratch
  __shared__ u16 Vt[64 * 136];       // V^T tile [dk][key]
  const int tid  = threadIdx.x;
  const int lane = tid & 63;
  const int w    = tid >> 6;
  const int n    = lane & 31;
  const int h    = lane >> 5;        // lane half
  // swizzled decode
  const int bid = blockIdx.x;
  const int s5  = bid >> 3;
  const int p   = (bid & 7) + 8 * (s5 >> 4);   // (b,h) pair 0..63
  const int qt  = 15 - (s5 & 15);              // big blocks first
  const int hd  = p & 15, b = p >> 4;
  const int q0 = qt * 128;
  const int qw = q0 + w * 32;        // wave's q-row base
  const size_t kbase = ((size_t)b * S_LEN) * D_MODEL + (size_t)hd * DK;
  const size_t vbase = ((size_t)hd * DK) * M_TOTAL + (size_t)b * S_LEN;

  // Q B-frags (n = q-row = lane&31, k = dk = ks*16 + h*8 + j), held in regs
  s16x8 bq[4];
#pragma unroll
  for (int ks = 0; ks < 4; ks++)
    bq[ks] = *(const s16x8*)(Qb + kbase + (size_t)(qw + n) * D_MODEL + ks * 16 + h * 8);

  f32x16 o0, o1;
#pragma unroll
  for (int i = 0; i < 16; i++) { o0[i] = 0.f; o1[i] = 0.f; }
  float psum = 0.f;

  uint4 gk[4], gv[4];
#pragma unroll
  for (int pld = 0; pld < 4; pld++) {
    int idx = pld * 256 + tid;
    gk[pld] = *(const uint4*)(Kb + kbase + (size_t)(idx >> 3) * D_MODEL + (idx & 7) * 8);
    gv[pld] = *(const uint4*)(Vtg + vbase + (size_t)(idx >> 4) * M_TOTAL + (idx & 15) * 8);
  }

  const int ktiles = qt + 1;
  for (int t = 0; t < ktiles; t++) {
    const int k0 = t * 128;
    __syncthreads();
#pragma unroll
    for (int pld = 0; pld < 4; pld++) {
      int idx = pld * 256 + tid;
      *(uint4*)(Kl + (idx >> 3) * 72 + (idx & 7) * 8) = gk[pld];
      *(uint4*)(Vt + (idx >> 4) * 136 + (idx & 15) * 8) = gv[pld];
    }
    __syncthreads();
    if (t + 1 < ktiles) {
      const int kn = k0 + 128;
#pragma unroll
      for (int pld = 0; pld < 4; pld++) {
        int idx = pld * 256 + tid;
        gk[pld] = *(const uint4*)(Kb + kbase + (size_t)(kn + (idx >> 3)) * D_MODEL + (idx & 7) * 8);
        gv[pld] = *(const uint4*)(Vtg + vbase + (size_t)(idx >> 4) * M_TOTAL + kn + (idx & 15) * 8);
      }
    }

#pragma unroll
    for (int kt = 0; kt < 4; kt++) {
      const int k0t = k0 + kt * 32;
      if (k0t > qw + 31) continue;          // fully masked 32-key sub-tile

      f32x16 Sc;
#pragma unroll
      for (int i = 0; i < 16; i++) Sc[i] = 0.f;
#pragma unroll
      for (int ks = 0; ks < 4; ks++) {
        s16x8 ak = *(const s16x8*)(Kl + (kt * 32 + n) * 72 + ks * 16 + h * 8);
        Sc = __builtin_amdgcn_mfma_f32_32x32x16_bf16(ak, bq[ks], Sc, 0, 0, 0);
      }

      const bool needmask = (k0t + 31) > qw;
      u32 P0[4], P1[4];
#pragma unroll
      for (int g = 0; g < 4; g++) {
        float pv[4];
#pragma unroll
        for (int t2 = 0; t2 < 4; t2++) {
          float v = Sc[4 * g + t2];
          if (needmask) {
            int key = k0t + 8 * g + t2 + 4 * h;
            v = (key <= qw + n) ? v : -1e30f;
          }
          pv[t2] = exp2f(v);
          psum += pv[t2];
        }
        P0[g] = packtrunc(pv[0], pv[1]);
        P1[g] = packtrunc(pv[2], pv[3]);
      }

#pragma unroll
      for (int c = 0; c < 2; c++) {
        u32 X0 = h ? P0[2 * c + 1] : P0[2 * c];
        u32 X1 = h ? P1[2 * c + 1] : P1[2 * c];
        u32 Y0 = h ? P0[2 * c]     : P0[2 * c + 1];
        u32 Y1 = h ? P1[2 * c]     : P1[2 * c + 1];
        u32 Z0 = (u32)__shfl_xor((int)Y0, 32);
        u32 Z1 = (u32)__shfl_xor((int)Y1, 32);
        union { u32 u[4]; s16x8 v; } pb;
        pb.u[0] = h ? Z0 : X0;
        pb.u[1] = h ? Z1 : X1;
        pb.u[2] = h ? X0 : Z0;
        pb.u[3] = h ? X1 : Z1;
        {
          s16x8 vf0 = *(const s16x8*)(Vt + (0 * 32 + n) * 136 + kt * 32 + c * 16 + h * 8);
          o0 = __builtin_amdgcn_mfma_f32_32x32x16_bf16(vf0, pb.v, o0, 0, 0, 0);
          s16x8 vf1 = *(const s16x8*)(Vt + (1 * 32 + n) * 136 + kt * 32 + c * 16 + h * 8);
          o1 = __builtin_amdgcn_mfma_f32_32x32x16_bf16(vf1, pb.v, o1, 0, 0, 0);
        }
      }
    }
  }

  // ---- epilogue: l; O^T -> row-major through LDS; full-line global stores --
  float l = psum + __shfl_xor(psum, 32);
  const float linv = 1.0f / l;
  __syncthreads();                    // all waves done with Kl/Vt; reuse Kl
  u16* Olw = Kl + w * 32 * 66;        // per-wave [32 qrow][64 dk], stride 66
#pragma unroll
  for (int dt = 0; dt < 2; dt++) {
    const f32x16& o = dt ? o1 : o0;
#pragma unroll
    for (int g = 0; g < 4; g++) {
      u32 lo = packrn(o[4 * g + 0] * linv, o[4 * g + 1] * linv);
      u32 hi = packrn(o[4 * g + 2] * linv, o[4 * g + 3] * linv);
      *(uint2*)(Olw + n * 66 + dt * 32 + 8 * g + 4 * h) = (uint2){lo, hi};
    }
  }
  // read back row-major: 8 lanes cover one row's 128B head-slice per instr
  const int rr = lane >> 3, seg = lane & 7;
#pragma unroll
  for (int ro = 0; ro < 32; ro += 8) {
    uint4 v = *(const uint4*)(Olw + (ro + rr) * 66 + seg * 8);
    *(uint4*)(Mh + ((size_t)b * S_LEN + qw + ro + rr) * D_MODEL + hd * DK + seg * 8) = v;
  }
}

extern "C" void kernel_launch(void* const* d_in, const int* in_sizes, int n_in,
                              void* d_out, int out_size, void* d_ws, size_t ws_size,
                              hipStream_t stream) {
  const float* x  = (const float*)d_in[0];
  const float* Wq = (const float*)d_in[1];
  const float* Wk = (const float*)d_in[2];
  const float* Wv = (const float*)d_in[3];
  const float* Wo = (const float*)d_in[4];
  float* out = (float*)d_out;

  char* ws = (char*)d_ws;
  const size_t xsz = (size_t)M_TOTAL * D_MODEL * 2;
  const size_t wsz = (size_t)D_MODEL * D_MODEL * 2;
  u16* Xb  = (u16*)ws; ws += xsz;
  u16* Wqb = (u16*)ws; ws += wsz;
  u16* Wkb = (u16*)ws; ws += wsz;
  u16* Wvb = (u16*)ws; ws += wsz;
  u16* Wob = (u16*)ws; ws += wsz;
  u16* Qb  = (u16*)ws; ws += xsz;
  u16* Kb  = (u16*)ws; ws += xsz;
  u16* Vtg = (u16*)ws; ws += xsz;   // V transposed: [1024][8192]
  u16* Mh  = (u16*)ws; ws += xsz;

  {
    int n4 = M_TOTAL * D_MODEL / 4;
    k_f2bf<<<(n4 + 255) / 256, 256, 0, stream>>>(x, Xb, n4);
    n4 = D_MODEL * D_MODEL / 4;
    int blk = (n4 + 255) / 256;
    k_f2bf<<<blk, 256, 0, stream>>>(Wq, Wqb, n4);
    k_f2bf<<<blk, 256, 0, stream>>>(Wk, Wkb, n4);
    k_f2bf<<<blk, 256, 0, stream>>>(Wv, Wvb, n4);
    k_f2bf<<<blk, 256, 0, stream>>>(Wo, Wob, n4);
  }

  dim3 gg(D_MODEL / 128, M_TOTAL / 128);
  k_gemm<true, true><<<gg, 256, 0, stream>>>(Xb, Wqb, Qb, M_TOTAL, D_MODEL, D_MODEL, QSCALE);
  k_gemm<true, true><<<gg, 256, 0, stream>>>(Xb, Wkb, Kb, M_TOTAL, D_MODEL, D_MODEL, 1.0f);
  dim3 gv(M_TOTAL / 128, D_MODEL / 128);
  k_gemm<true, false><<<gv, 256, 0, stream>>>(Wvb, Xb, Vtg, D_MODEL, M_TOTAL, D_MODEL, 1.0f);

  k_attn<<<dim3(1024), 256, 0, stream>>>(Qb, Kb, Vtg, Mh);

  k_gemm<false, false><<<gg, 256, 0, stream>>>(Mh, Wob, out, M_TOTAL, D_MODEL, D_MODEL, 1.0f);
}

// Round 6
// 393.366 us; speedup vs baseline: 1.3785x; 1.0269x over previous
//
#include <hip/hip_runtime.h>

typedef unsigned short u16;
typedef unsigned int   u32;
typedef __attribute__((ext_vector_type(8))) short s16x8;
typedef __attribute__((ext_vector_type(4))) float f32x4;
typedef __attribute__((ext_vector_type(16))) float f32x16;

#define D_MODEL 1024
#define S_LEN   2048
#define BATCH   4
#define HEADS   16
#define DK      64
#define M_TOTAL (BATCH * S_LEN)   // 8192

// Q scale: 1/sqrt(64) * log2(e)  (scores produced in log2 domain for exp2)
#define QSCALE 0.18033688011112042f
// log2(10000)/32
#define ROPE_L2 0.41524101186092029f

__device__ __forceinline__ u16 f2b(float f) {
  u32 u = __float_as_uint(f);
  u32 r = u + 0x7FFFu + ((u >> 16) & 1u);
  return (u16)(r >> 16);
}
// pack two positive floats to bf16x2 (truncation — P weights only)
__device__ __forceinline__ u32 packtrunc(float f0, float f1) {
  return (__float_as_uint(f0) >> 16) | (__float_as_uint(f1) & 0xFFFF0000u);
}
// round-to-nearest pack
__device__ __forceinline__ u32 packrn(float f0, float f1) {
  return (u32)f2b(f0) | ((u32)f2b(f1) << 16);
}

typedef const __attribute__((address_space(1))) unsigned int* gas_u32p;
typedef __attribute__((address_space(3))) unsigned int* las_u32p;
#define GLL16(gp, lp) __builtin_amdgcn_global_load_lds((gas_u32p)(gp), (las_u32p)(lp), 16, 0, 0)

// ---------------- fp32 -> bf16 convert, 4 elems/thread ----------------
__global__ void k_f2bf(const float* __restrict__ in, u16* __restrict__ out, int n4) {
  int i = blockIdx.x * blockDim.x + threadIdx.x;
  if (i >= n4) return;
  float4 v = ((const float4*)in)[i];
  ((u32*)out)[2*i]   = packrn(v.x, v.y);
  ((u32*)out)[2*i+1] = packrn(v.z, v.w);
}

// ---------------- GEMM: C[m][n] = sum_k A[m][k] * B[n][k]  (both K-major bf16)
// m97 recipe: 128x128 tile, BK=32, unpadded LDS, global_load_lds width 16.
template<bool BF16OUT, bool ROPE>
__launch_bounds__(256, 4)
__global__ void k_gemm(const u16* __restrict__ A, const u16* __restrict__ B,
                       void* __restrict__ C, int M, int N, int K, float scale) {
  __shared__ u16 Al[128 * 32];
  __shared__ u16 Bl[128 * 32];
  const int tid  = threadIdx.x;
  const int lane = tid & 63;
  const int w    = tid >> 6;
  const int wm   = (w >> 1) * 64, wn = (w & 1) * 64;
  const int bm   = blockIdx.y * 128, bn = blockIdx.x * 128;
  const int row  = lane & 15, q = lane >> 4;

  f32x4 acc[4][4];
#pragma unroll
  for (int i = 0; i < 4; i++)
#pragma unroll
    for (int j = 0; j < 4; j++) acc[i][j] = (f32x4){0.f, 0.f, 0.f, 0.f};

  const int r16 = lane >> 2;
  const int cb  = (lane & 3) * 8;
  const u16* Ag0 = A + (size_t)(bm + w * 32 + r16) * K + cb;
  const u16* Ag1 = Ag0 + (size_t)16 * K;
  const u16* Bg0 = B + (size_t)(bn + w * 32 + r16) * K + cb;
  const u16* Bg1 = Bg0 + (size_t)16 * K;
  u16* Ad0 = Al + (w * 32) * 32;
  u16* Ad1 = Al + (w * 32 + 16) * 32;
  u16* Bd0 = Bl + (w * 32) * 32;
  u16* Bd1 = Bl + (w * 32 + 16) * 32;

  for (int k0 = 0; k0 < K; k0 += 32) {
    __syncthreads();
    GLL16(Ag0 + k0, Ad0);
    GLL16(Ag1 + k0, Ad1);
    GLL16(Bg0 + k0, Bd0);
    GLL16(Bg1 + k0, Bd1);
    __syncthreads();
    s16x8 af[4], bfr[4];
#pragma unroll
    for (int mi = 0; mi < 4; mi++)
      af[mi] = *(const s16x8*)(Al + (wm + mi * 16 + row) * 32 + q * 8);
#pragma unroll
    for (int ni = 0; ni < 4; ni++)
      bfr[ni] = *(const s16x8*)(Bl + (wn + ni * 16 + row) * 32 + q * 8);
#pragma unroll
    for (int mi = 0; mi < 4; mi++)
#pragma unroll
      for (int ni = 0; ni < 4; ni++)
        acc[mi][ni] = __builtin_amdgcn_mfma_f32_16x16x32_bf16(af[mi], bfr[ni], acc[mi][ni], 0, 0, 0);
  }

#pragma unroll
  for (int mi = 0; mi < 4; mi++)
#pragma unroll
    for (int ni = 0; ni < 4; ni++) {
      if (ROPE) {
        const int col = bn + wn + ni * 16 + row;
        const int fi  = (col & 63) >> 1;
        const float inv = exp2f(-(float)fi * ROPE_L2);
        const bool odd = (row & 1);
#pragma unroll
        for (int r = 0; r < 4; r++) {
          int grow = bm + wm + mi * 16 + q * 4 + r;
          float own = acc[mi][ni][r];
          float oth = __shfl_xor(own, 1);
          float ang = (float)(grow & (S_LEN - 1)) * inv;
          float sn, cs;
          __sincosf(ang, &sn, &cs);
          float x1 = odd ? oth : own;
          float x2 = odd ? own : oth;
          float res = odd ? (x1 * sn + x2 * cs) : (x1 * cs - x2 * sn);
          acc[mi][ni][r] = res * scale;
        }
      }
#pragma unroll
      for (int r = 0; r < 4; r++) {
        int grow = bm + wm + mi * 16 + q * 4 + r;
        int gcol = bn + wn + ni * 16 + row;
        float v = acc[mi][ni][r];
        if (BF16OUT) ((u16*)C)[(size_t)grow * N + gcol] = f2b(v);
        else         ((float*)C)[(size_t)grow * N + gcol] = v;
      }
    }
}

// ---------------- flash attention (causal), 32x32 MFMA, 64 q-rows/wave -----
// S^T = K·Q^T; wave owns TWO 32-row q-strips so each K/V fragment read from
// LDS feeds 2x the MFMA work (DS-pipe is the measured bottleneck).
// Block = 256 q-rows, 4 waves; grid 512 blocks XCD-swizzled (pair pinned to
// one XCD, qt descending). V pre-transposed: Vtg[h*64+dk][b*2048+s].
__launch_bounds__(256, 2)
__global__ void k_attn(const u16* __restrict__ Qb, const u16* __restrict__ Kb,
                       const u16* __restrict__ Vtg, u16* __restrict__ Mh) {
  __shared__ u16 SH[128 * 72 + 64 * 136];   // Kl | Vt; reused for O transpose
  u16* Kl = SH;
  u16* Vt = SH + 128 * 72;
  const int tid  = threadIdx.x;
  const int lane = tid & 63;
  const int w    = tid >> 6;
  const int n    = lane & 31;
  const int h    = lane >> 5;        // lane half
  // swizzled decode: XCD = bid&7 gets pairs {x, x+8, ...}; qt descending
  const int bid = blockIdx.x;
  const int s5  = bid >> 3;
  const int p   = (bid & 7) + 8 * (s5 >> 3);   // (b,h) pair 0..63
  const int t8  = 7 - (s5 & 7);                // q-block index, big first
  const int hd  = p & 15, b = p >> 4;
  const int q0 = t8 * 256;
  const int qw = q0 + w * 64;        // wave's q-row base (64 rows, 2 strips)
  const size_t kbase = ((size_t)b * S_LEN) * D_MODEL + (size_t)hd * DK;
  const size_t vbase = ((size_t)hd * DK) * M_TOTAL + (size_t)b * S_LEN;

  // Q B-frags for both strips (n = q-row = lane&31, k = dk = ks*16 + h*8 + j)
  s16x8 bq[2][4];
#pragma unroll
  for (int s = 0; s < 2; s++)
#pragma unroll
    for (int ks = 0; ks < 4; ks++)
      bq[s][ks] = *(const s16x8*)(Qb + kbase + (size_t)(qw + s * 32 + n) * D_MODEL + ks * 16 + h * 8);

  f32x16 o[2][2];
#pragma unroll
  for (int s = 0; s < 2; s++)
#pragma unroll
    for (int dt = 0; dt < 2; dt++)
#pragma unroll
      for (int i = 0; i < 16; i++) o[s][dt][i] = 0.f;
  float psum[2] = {0.f, 0.f};

  uint4 gk[4], gv[4];
#pragma unroll
  for (int pld = 0; pld < 4; pld++) {
    int idx = pld * 256 + tid;
    gk[pld] = *(const uint4*)(Kb + kbase + (size_t)(idx >> 3) * D_MODEL + (idx & 7) * 8);
    gv[pld] = *(const uint4*)(Vtg + vbase + (size_t)(idx >> 4) * M_TOTAL + (idx & 15) * 8);
  }

  const int ktiles = 2 * t8 + 2;
  for (int t = 0; t < ktiles; t++) {
    const int k0 = t * 128;
    __syncthreads();
#pragma unroll
    for (int pld = 0; pld < 4; pld++) {
      int idx = pld * 256 + tid;
      *(uint4*)(Kl + (idx >> 3) * 72 + (idx & 7) * 8) = gk[pld];
      *(uint4*)(Vt + (idx >> 4) * 136 + (idx & 15) * 8) = gv[pld];
    }
    __syncthreads();
    if (t + 1 < ktiles) {
      const int kn = k0 + 128;
#pragma unroll
      for (int pld = 0; pld < 4; pld++) {
        int idx = pld * 256 + tid;
        gk[pld] = *(const uint4*)(Kb + kbase + (size_t)(kn + (idx >> 3)) * D_MODEL + (idx & 7) * 8);
        gv[pld] = *(const uint4*)(Vtg + vbase + (size_t)(idx >> 4) * M_TOTAL + kn + (idx & 15) * 8);
      }
    }

#pragma unroll
    for (int kt = 0; kt < 4; kt++) {
      const int k0t = k0 + kt * 32;
      if (k0t > qw + 95) continue;          // masked for both strips (wave-uniform)

      // fragments loaded ONCE, reused by both strips
      s16x8 ak[4], vf[4];
#pragma unroll
      for (int ks = 0; ks < 4; ks++)
        ak[ks] = *(const s16x8*)(Kl + (kt * 32 + n) * 72 + ks * 16 + h * 8);
#pragma unroll
      for (int c = 0; c < 2; c++)
#pragma unroll
        for (int dt = 0; dt < 2; dt++)
          vf[c * 2 + dt] = *(const s16x8*)(Vt + (dt * 32 + n) * 136 + kt * 32 + c * 16 + h * 8);

#pragma unroll
      for (int s = 0; s < 2; s++) {
        const int rb = qw + s * 32;
        if (k0t > rb + 31) continue;        // strip fully masked

        f32x16 Sc;
#pragma unroll
        for (int i = 0; i < 16; i++) Sc[i] = 0.f;
#pragma unroll
        for (int ks = 0; ks < 4; ks++)
          Sc = __builtin_amdgcn_mfma_f32_32x32x16_bf16(ak[ks], bq[s][ks], Sc, 0, 0, 0);

        const bool needmask = (k0t + 31) > rb;
        u32 P0[4], P1[4];
        float ps = 0.f;
#pragma unroll
        for (int g = 0; g < 4; g++) {
          float pv[4];
#pragma unroll
          for (int t2 = 0; t2 < 4; t2++) {
            float v = Sc[4 * g + t2];
            if (needmask) {
              int key = k0t + 8 * g + t2 + 4 * h;
              v = (key <= rb + n) ? v : -1e30f;
            }
            pv[t2] = exp2f(v);
            ps += pv[t2];
          }
          P0[g] = packtrunc(pv[0], pv[1]);
          P1[g] = packtrunc(pv[2], pv[3]);
        }
        psum[s] += ps;

#pragma unroll
        for (int c = 0; c < 2; c++) {
          u32 X0 = h ? P0[2 * c + 1] : P0[2 * c];
          u32 X1 = h ? P1[2 * c + 1] : P1[2 * c];
          u32 Y0 = h ? P0[2 * c]     : P0[2 * c + 1];
          u32 Y1 = h ? P1[2 * c]     : P1[2 * c + 1];
          u32 Z0 = (u32)__shfl_xor((int)Y0, 32);
          u32 Z1 = (u32)__shfl_xor((int)Y1, 32);
          union { u32 u[4]; s16x8 v; } pb;
          pb.u[0] = h ? Z0 : X0;
          pb.u[1] = h ? Z1 : X1;
          pb.u[2] = h ? X0 : Z0;
          pb.u[3] = h ? X1 : Z1;
          o[s][0] = __builtin_amdgcn_mfma_f32_32x32x16_bf16(vf[c * 2 + 0], pb.v, o[s][0], 0, 0, 0);
          o[s][1] = __builtin_amdgcn_mfma_f32_32x32x16_bf16(vf[c * 2 + 1], pb.v, o[s][1], 0, 0, 0);
        }
      }
    }
  }

  // ---- epilogue: two passes (one per strip) through LDS for coalesced stores
  const int rr = lane >> 3, seg = lane & 7;
#pragma unroll
  for (int s = 0; s < 2; s++) {
    float l = psum[s] + __shfl_xor(psum[s], 32);
    const float linv = 1.0f / l;
    __syncthreads();                  // LDS region free (staging / prev pass)
    u16* Olw = SH + w * 32 * 66;      // per-wave [32 qrow][64 dk], stride 66
#pragma unroll
    for (int dt = 0; dt < 2; dt++) {
#pragma unroll
      for (int g = 0; g < 4; g++) {
        u32 lo = packrn(o[s][dt][4 * g + 0] * linv, o[s][dt][4 * g + 1] * linv);
        u32 hi = packrn(o[s][dt][4 * g + 2] * linv, o[s][dt][4 * g + 3] * linv);
        *(uint2*)(Olw + n * 66 + dt * 32 + 8 * g + 4 * h) = (uint2){lo, hi};
      }
    }
#pragma unroll
    for (int ro = 0; ro < 32; ro += 8) {
      uint4 v = *(const uint4*)(Olw + (ro + rr) * 66 + seg * 8);
      *(uint4*)(Mh + ((size_t)b * S_LEN + qw + s * 32 + ro + rr) * D_MODEL + hd * DK + seg * 8) = v;
    }
  }
}

extern "C" void kernel_launch(void* const* d_in, const int* in_sizes, int n_in,
                              void* d_out, int out_size, void* d_ws, size_t ws_size,
                              hipStream_t stream) {
  const float* x  = (const float*)d_in[0];
  const float* Wq = (const float*)d_in[1];
  const float* Wk = (const float*)d_in[2];
  const float* Wv = (const float*)d_in[3];
  const float* Wo = (const float*)d_in[4];
  float* out = (float*)d_out;

  char* ws = (char*)d_ws;
  const size_t xsz = (size_t)M_TOTAL * D_MODEL * 2;
  const size_t wsz = (size_t)D_MODEL * D_MODEL * 2;
  u16* Xb  = (u16*)ws; ws += xsz;
  u16* Wqb = (u16*)ws; ws += wsz;
  u16* Wkb = (u16*)ws; ws += wsz;
  u16* Wvb = (u16*)ws; ws += wsz;
  u16* Wob = (u16*)ws; ws += wsz;
  u16* Qb  = (u16*)ws; ws += xsz;
  u16* Kb  = (u16*)ws; ws += xsz;
  u16* Vtg = (u16*)ws; ws += xsz;   // V transposed: [1024][8192]
  u16* Mh  = (u16*)ws; ws += xsz;

  {
    int n4 = M_TOTAL * D_MODEL / 4;
    k_f2bf<<<(n4 + 255) / 256, 256, 0, stream>>>(x, Xb, n4);
    n4 = D_MODEL * D_MODEL / 4;
    int blk = (n4 + 255) / 256;
    k_f2bf<<<blk, 256, 0, stream>>>(Wq, Wqb, n4);
    k_f2bf<<<blk, 256, 0, stream>>>(Wk, Wkb, n4);
    k_f2bf<<<blk, 256, 0, stream>>>(Wv, Wvb, n4);
    k_f2bf<<<blk, 256, 0, stream>>>(Wo, Wob, n4);
  }

  dim3 gg(D_MODEL / 128, M_TOTAL / 128);
  k_gemm<true, true><<<gg, 256, 0, stream>>>(Xb, Wqb, Qb, M_TOTAL, D_MODEL, D_MODEL, QSCALE);
  k_gemm<true, true><<<gg, 256, 0, stream>>>(Xb, Wkb, Kb, M_TOTAL, D_MODEL, D_MODEL, 1.0f);
  dim3 gv(M_TOTAL / 128, D_MODEL / 128);
  k_gemm<true, false><<<gv, 256, 0, stream>>>(Wvb, Xb, Vtg, D_MODEL, M_TOTAL, D_MODEL, 1.0f);

  k_attn<<<dim3(512), 256, 0, stream>>>(Qb, Kb, Vtg, Mh);

  k_gemm<false, false><<<gg, 256, 0, stream>>>(Mh, Wob, out, M_TOTAL, D_MODEL, D_MODEL, 1.0f);
}

// Round 7
// 329.812 us; speedup vs baseline: 1.6441x; 1.1927x over previous
//
#include <hip/hip_runtime.h>

typedef unsigned short u16;
typedef unsigned int   u32;
typedef __attribute__((ext_vector_type(8))) short s16x8;
typedef __attribute__((ext_vector_type(4))) float f32x4;
typedef __attribute__((ext_vector_type(16))) float f32x16;

#define D_MODEL 1024
#define S_LEN   2048
#define BATCH   4
#define HEADS   16
#define DK      64
#define M_TOTAL (BATCH * S_LEN)   // 8192

// Q scale: 1/sqrt(64) * log2(e)  (scores produced in log2 domain for exp2)
#define QSCALE 0.18033688011112042f
// log2(10000)/32
#define ROPE_L2 0.41524101186092029f

__device__ __forceinline__ u16 f2b(float f) {
  u32 u = __float_as_uint(f);
  u32 r = u + 0x7FFFu + ((u >> 16) & 1u);
  return (u16)(r >> 16);
}
// pack two positive floats to bf16x2 (truncation — P weights only)
__device__ __forceinline__ u32 packtrunc(float f0, float f1) {
  return (__float_as_uint(f0) >> 16) | (__float_as_uint(f1) & 0xFFFF0000u);
}
// round-to-nearest pack
__device__ __forceinline__ u32 packrn(float f0, float f1) {
  return (u32)f2b(f0) | ((u32)f2b(f1) << 16);
}

typedef const __attribute__((address_space(1))) unsigned int* gas_u32p;
typedef __attribute__((address_space(3))) unsigned int* las_u32p;
#define GLL16(gp, lp) __builtin_amdgcn_global_load_lds((gas_u32p)(gp), (las_u32p)(lp), 16, 0, 0)

// ---------------- fp32 -> bf16 convert, 4 elems/thread ----------------
__global__ void k_f2bf(const float* __restrict__ in, u16* __restrict__ out, int n4) {
  int i = blockIdx.x * blockDim.x + threadIdx.x;
  if (i >= n4) return;
  float4 v = ((const float4*)in)[i];
  ((u32*)out)[2*i]   = packrn(v.x, v.y);
  ((u32*)out)[2*i+1] = packrn(v.z, v.w);
}

// four 1024x1024 weight matrices -> one contiguous bf16 buffer
__global__ void k_f2bf4(const float* __restrict__ a, const float* __restrict__ b,
                        const float* __restrict__ c, const float* __restrict__ d,
                        u16* __restrict__ out) {
  int i = blockIdx.x * blockDim.x + threadIdx.x;   // 4 * 262144 groups
  const float* src = (i < 524288) ? ((i < 262144) ? a : b) : ((i < 786432) ? c : d);
  int off = i & 0x3FFFF;
  float4 v = ((const float4*)src)[off];
  ((u32*)out)[2*i]   = packrn(v.x, v.y);
  ((u32*)out)[2*i+1] = packrn(v.z, v.w);
}

// ---------------- GEMM: C[m][n] = sum_k A[m][k] * B[n][k]  (both K-major bf16)
// m97 recipe: 128x128 tile, BK=32, unpadded LDS, global_load_lds width 16.
// DUAL: B has 2*D_MODEL rows (Wq||Wk); output column half selects C (Q) or C2 (K),
// Q half also gets 'scale' (QSCALE), K half scale 1.
template<bool BF16OUT, bool ROPE, bool DUAL>
__launch_bounds__(256, 4)
__global__ void k_gemm(const u16* __restrict__ A, const u16* __restrict__ B,
                       void* __restrict__ C, void* __restrict__ C2,
                       int M, int N, int K, float scale) {
  __shared__ u16 Al[128 * 32];
  __shared__ u16 Bl[128 * 32];
  const int tid  = threadIdx.x;
  const int lane = tid & 63;
  const int w    = tid >> 6;
  const int wm   = (w >> 1) * 64, wn = (w & 1) * 64;
  const int bm   = blockIdx.y * 128, bn = blockIdx.x * 128;
  const int row  = lane & 15, q = lane >> 4;

  f32x4 acc[4][4];
#pragma unroll
  for (int i = 0; i < 4; i++)
#pragma unroll
    for (int j = 0; j < 4; j++) acc[i][j] = (f32x4){0.f, 0.f, 0.f, 0.f};

  const int r16 = lane >> 2;
  const int cb  = (lane & 3) * 8;
  const u16* Ag0 = A + (size_t)(bm + w * 32 + r16) * K + cb;
  const u16* Ag1 = Ag0 + (size_t)16 * K;
  const u16* Bg0 = B + (size_t)(bn + w * 32 + r16) * K + cb;
  const u16* Bg1 = Bg0 + (size_t)16 * K;
  u16* Ad0 = Al + (w * 32) * 32;
  u16* Ad1 = Al + (w * 32 + 16) * 32;
  u16* Bd0 = Bl + (w * 32) * 32;
  u16* Bd1 = Bl + (w * 32 + 16) * 32;

  for (int k0 = 0; k0 < K; k0 += 32) {
    __syncthreads();
    GLL16(Ag0 + k0, Ad0);
    GLL16(Ag1 + k0, Ad1);
    GLL16(Bg0 + k0, Bd0);
    GLL16(Bg1 + k0, Bd1);
    __syncthreads();
    s16x8 af[4], bfr[4];
#pragma unroll
    for (int mi = 0; mi < 4; mi++)
      af[mi] = *(const s16x8*)(Al + (wm + mi * 16 + row) * 32 + q * 8);
#pragma unroll
    for (int ni = 0; ni < 4; ni++)
      bfr[ni] = *(const s16x8*)(Bl + (wn + ni * 16 + row) * 32 + q * 8);
#pragma unroll
    for (int mi = 0; mi < 4; mi++)
#pragma unroll
      for (int ni = 0; ni < 4; ni++)
        acc[mi][ni] = __builtin_amdgcn_mfma_f32_16x16x32_bf16(af[mi], bfr[ni], acc[mi][ni], 0, 0, 0);
  }

  const bool isQ = !DUAL || (bn < D_MODEL);
  u16* Cd = (u16*)(isQ ? C : C2);
  const int bnL = DUAL ? (bn & (D_MODEL - 1)) : bn;
  const float sc = isQ ? scale : 1.0f;

#pragma unroll
  for (int mi = 0; mi < 4; mi++)
#pragma unroll
    for (int ni = 0; ni < 4; ni++) {
      if (ROPE) {
        const int col = bnL + wn + ni * 16 + row;
        const int fi  = (col & 63) >> 1;
        const float inv = exp2f(-(float)fi * ROPE_L2);
        const bool odd = (row & 1);
#pragma unroll
        for (int r = 0; r < 4; r++) {
          int grow = bm + wm + mi * 16 + q * 4 + r;
          float own = acc[mi][ni][r];
          float oth = __shfl_xor(own, 1);
          float ang = (float)(grow & (S_LEN - 1)) * inv;
          float sn, cs;
          __sincosf(ang, &sn, &cs);
          float x1 = odd ? oth : own;
          float x2 = odd ? own : oth;
          float res = odd ? (x1 * sn + x2 * cs) : (x1 * cs - x2 * sn);
          acc[mi][ni][r] = res * sc;
        }
      }
#pragma unroll
      for (int r = 0; r < 4; r++) {
        int grow = bm + wm + mi * 16 + q * 4 + r;
        int gcol = bnL + wn + ni * 16 + row;
        float v = acc[mi][ni][r];
        if (BF16OUT) Cd[(size_t)grow * N + gcol] = f2b(v);
        else         ((float*)Cd)[(size_t)grow * N + gcol] = v;
      }
    }
}

// ---------------- flash attention (causal), 32x32 MFMA, wrap-paired --------
// Block p handles q-tiles {p, 15-p} of one (b,h): wave w owns strip-low
// (rows 128p+32w) and strip-high (rows 128(15-p)+32w). Work per wave is
// constant (~17 k-tile-strip units) -> no tail; dual strips give 2 independent
// chains. K/V tile staged once per k-tile, consumed by both strips.
// Grid 512 blocks XCD-swizzled. V pre-transposed: Vtg[h*64+dk][b*2048+s].
__launch_bounds__(256, 2)
__global__ void k_attn(const u16* __restrict__ Qb, const u16* __restrict__ Kb,
                       const u16* __restrict__ Vtg, u16* __restrict__ Mh) {
  __shared__ u16 SH[128 * 72 + 64 * 136];   // Kl | Vt; reused for O transpose
  u16* Kl = SH;
  u16* Vt = SH + 128 * 72;
  const int tid  = threadIdx.x;
  const int lane = tid & 63;
  const int w    = tid >> 6;
  const int n    = lane & 31;
  const int h    = lane >> 5;        // lane half
  // decode: XCD = bid&7; within XCD: 8 pair-indices x 8 (b,h)
  const int bid = blockIdx.x;        // 0..511
  const int r   = bid >> 3;          // 0..63
  const int p   = r & 7;             // pair index 0..7
  const int bh  = (bid & 7) + 8 * (r >> 3);   // 0..63
  const int hd  = bh & 15, b = bh >> 4;
  const int Tb  = 15 - p;            // high q-tile
  const int rb0 = p  * 128 + w * 32; // strip-low base q-row
  const int rb1 = Tb * 128 + w * 32; // strip-high base q-row
  const size_t kbase = ((size_t)b * S_LEN) * D_MODEL + (size_t)hd * DK;
  const size_t vbase = ((size_t)hd * DK) * M_TOTAL + (size_t)b * S_LEN;

  // Q B-frags for both strips (n = q-row = lane&31, k = dk = ks*16 + h*8 + j)
  s16x8 bq[2][4];
#pragma unroll
  for (int s = 0; s < 2; s++) {
    const int rb = s ? rb1 : rb0;
#pragma unroll
    for (int ks = 0; ks < 4; ks++)
      bq[s][ks] = *(const s16x8*)(Qb + kbase + (size_t)(rb + n) * D_MODEL + ks * 16 + h * 8);
  }

  f32x16 o[2][2];
#pragma unroll
  for (int s = 0; s < 2; s++)
#pragma unroll
    for (int dt = 0; dt < 2; dt++)
#pragma unroll
      for (int i = 0; i < 16; i++) o[s][dt][i] = 0.f;
  float psum[2] = {0.f, 0.f};

  uint4 gk[4], gv[4];
#pragma unroll
  for (int pld = 0; pld < 4; pld++) {
    int idx = pld * 256 + tid;
    gk[pld] = *(const uint4*)(Kb + kbase + (size_t)(idx >> 3) * D_MODEL + (idx & 7) * 8);
    gv[pld] = *(const uint4*)(Vtg + vbase + (size_t)(idx >> 4) * M_TOTAL + (idx & 15) * 8);
  }

  const int ktiles = Tb + 1;
  for (int t = 0; t < ktiles; t++) {
    const int k0 = t * 128;
    __syncthreads();
#pragma unroll
    for (int pld = 0; pld < 4; pld++) {
      int idx = pld * 256 + tid;
      *(uint4*)(Kl + (idx >> 3) * 72 + (idx & 7) * 8) = gk[pld];
      *(uint4*)(Vt + (idx >> 4) * 136 + (idx & 15) * 8) = gv[pld];
    }
    __syncthreads();
    if (t + 1 < ktiles) {
      const int kn = k0 + 128;
#pragma unroll
      for (int pld = 0; pld < 4; pld++) {
        int idx = pld * 256 + tid;
        gk[pld] = *(const uint4*)(Kb + kbase + (size_t)(kn + (idx >> 3)) * D_MODEL + (idx & 7) * 8);
        gv[pld] = *(const uint4*)(Vtg + vbase + (size_t)(idx >> 4) * M_TOTAL + kn + (idx & 15) * 8);
      }
    }

#pragma unroll
    for (int kt = 0; kt < 4; kt++) {
      const int k0t = k0 + kt * 32;
      if (k0t > rb1 + 31) continue;         // beyond even the high strip

      // fragments loaded ONCE, reused by both strips
      s16x8 ak[4], vf[4];
#pragma unroll
      for (int ks = 0; ks < 4; ks++)
        ak[ks] = *(const s16x8*)(Kl + (kt * 32 + n) * 72 + ks * 16 + h * 8);
#pragma unroll
      for (int c = 0; c < 2; c++)
#pragma unroll
        for (int dt = 0; dt < 2; dt++)
          vf[c * 2 + dt] = *(const s16x8*)(Vt + (dt * 32 + n) * 136 + kt * 32 + c * 16 + h * 8);

#pragma unroll
      for (int s = 0; s < 2; s++) {
        const int rb = s ? rb1 : rb0;
        if (k0t > rb + 31) continue;        // strip fully masked

        f32x16 Sc;
#pragma unroll
        for (int i = 0; i < 16; i++) Sc[i] = 0.f;
#pragma unroll
        for (int ks = 0; ks < 4; ks++)
          Sc = __builtin_amdgcn_mfma_f32_32x32x16_bf16(ak[ks], bq[s][ks], Sc, 0, 0, 0);

        const bool needmask = (k0t + 31) > rb;
        u32 P0[4], P1[4];
        float ps = 0.f;
#pragma unroll
        for (int g = 0; g < 4; g++) {
          float pv[4];
#pragma unroll
          for (int t2 = 0; t2 < 4; t2++) {
            float v = Sc[4 * g + t2];
            if (needmask) {
              int key = k0t + 8 * g + t2 + 4 * h;
              v = (key <= rb + n) ? v : -1e30f;
            }
            pv[t2] = exp2f(v);
            ps += pv[t2];
          }
          P0[g] = packtrunc(pv[0], pv[1]);
          P1[g] = packtrunc(pv[2], pv[3]);
        }
        psum[s] += ps;

#pragma unroll
        for (int c = 0; c < 2; c++) {
          u32 X0 = h ? P0[2 * c + 1] : P0[2 * c];
          u32 X1 = h ? P1[2 * c + 1] : P1[2 * c];
          u32 Y0 = h ? P0[2 * c]     : P0[2 * c + 1];
          u32 Y1 = h ? P1[2 * c]     : P1[2 * c + 1];
          u32 Z0 = (u32)__shfl_xor((int)Y0, 32);
          u32 Z1 = (u32)__shfl_xor((int)Y1, 32);
          union { u32 u[4]; s16x8 v; } pb;
          pb.u[0] = h ? Z0 : X0;
          pb.u[1] = h ? Z1 : X1;
          pb.u[2] = h ? X0 : Z0;
          pb.u[3] = h ? X1 : Z1;
          o[s][0] = __builtin_amdgcn_mfma_f32_32x32x16_bf16(vf[c * 2 + 0], pb.v, o[s][0], 0, 0, 0);
          o[s][1] = __builtin_amdgcn_mfma_f32_32x32x16_bf16(vf[c * 2 + 1], pb.v, o[s][1], 0, 0, 0);
        }
      }
    }
  }

  // ---- epilogue: two passes (one per strip) through LDS for coalesced stores
  const int rr = lane >> 3, seg = lane & 7;
#pragma unroll
  for (int s = 0; s < 2; s++) {
    const int rb = s ? rb1 : rb0;
    float l = psum[s] + __shfl_xor(psum[s], 32);
    const float linv = 1.0f / l;
    __syncthreads();
    u16* Olw = SH + w * 32 * 66;      // per-wave [32 qrow][64 dk], stride 66
#pragma unroll
    for (int dt = 0; dt < 2; dt++) {
#pragma unroll
      for (int g = 0; g < 4; g++) {
        u32 lo = packrn(o[s][dt][4 * g + 0] * linv, o[s][dt][4 * g + 1] * linv);
        u32 hi = packrn(o[s][dt][4 * g + 2] * linv, o[s][dt][4 * g + 3] * linv);
        *(uint2*)(Olw + n * 66 + dt * 32 + 8 * g + 4 * h) = (uint2){lo, hi};
      }
    }
#pragma unroll
    for (int ro = 0; ro < 32; ro += 8) {
      uint4 v = *(const uint4*)(Olw + (ro + rr) * 66 + seg * 8);
      *(uint4*)(Mh + ((size_t)b * S_LEN + rb + ro + rr) * D_MODEL + hd * DK + seg * 8) = v;
    }
  }
}

extern "C" void kernel_launch(void* const* d_in, const int* in_sizes, int n_in,
                              void* d_out, int out_size, void* d_ws, size_t ws_size,
                              hipStream_t stream) {
  const float* x  = (const float*)d_in[0];
  const float* Wq = (const float*)d_in[1];
  const float* Wk = (const float*)d_in[2];
  const float* Wv = (const float*)d_in[3];
  const float* Wo = (const float*)d_in[4];
  float* out = (float*)d_out;

  char* ws = (char*)d_ws;
  const size_t xsz = (size_t)M_TOTAL * D_MODEL * 2;
  const size_t wsz = (size_t)D_MODEL * D_MODEL * 2;
  u16* Xb  = (u16*)ws; ws += xsz;
  u16* Wqb = (u16*)ws; ws += wsz;   // Wqb..Wob contiguous (k_f2bf4 + DUAL gemm rely on it)
  u16* Wkb = (u16*)ws; ws += wsz;
  u16* Wvb = (u16*)ws; ws += wsz;
  u16* Wob = (u16*)ws; ws += wsz;
  u16* Qb  = (u16*)ws; ws += xsz;
  u16* Kb  = (u16*)ws; ws += xsz;
  u16* Vtg = (u16*)ws; ws += xsz;   // V transposed: [1024][8192]
  u16* Mh  = (u16*)ws; ws += xsz;

  {
    int n4 = M_TOTAL * D_MODEL / 4;
    k_f2bf<<<(n4 + 255) / 256, 256, 0, stream>>>(x, Xb, n4);
    k_f2bf4<<<4096, 256, 0, stream>>>(Wq, Wk, Wv, Wo, Wqb);
  }

  // fused Q+K projection with RoPE epilogue (Q half also scaled by QSCALE)
  dim3 gqk(2 * D_MODEL / 128, M_TOTAL / 128);
  k_gemm<true, true, true><<<gqk, 256, 0, stream>>>(Xb, Wqb, Qb, Kb, M_TOTAL, D_MODEL, D_MODEL, QSCALE);
  // V projection computed TRANSPOSED
  dim3 gv(M_TOTAL / 128, D_MODEL / 128);
  k_gemm<true, false, false><<<gv, 256, 0, stream>>>(Wvb, Xb, Vtg, Vtg, D_MODEL, M_TOTAL, D_MODEL, 1.0f);

  k_attn<<<dim3(512), 256, 0, stream>>>(Qb, Kb, Vtg, Mh);

  dim3 gg(D_MODEL / 128, M_TOTAL / 128);
  k_gemm<false, false, false><<<gg, 256, 0, stream>>>(Mh, Wob, out, out, M_TOTAL, D_MODEL, D_MODEL, 1.0f);
}